// Round 8
// baseline (176.814 us; speedup 1.0000x reference)
//
#include <hip/hip_runtime.h>
#include <hip/hip_bf16.h>

#define P_TOT 32768   // H*W
#define O_QKV 768

using f32x2   = float  __attribute__((ext_vector_type(2)));
using f32x4   = float  __attribute__((ext_vector_type(4)));
using bf16x8  = __bf16 __attribute__((ext_vector_type(8)));
using ushort8 = unsigned short __attribute__((ext_vector_type(8)));

typedef __attribute__((address_space(1))) void* gptr_t;
typedef __attribute__((address_space(3))) void* sptr_t;
// async global->LDS, 16B per lane, dest = uniform base + lane*16
#define GLL16(g, l) __builtin_amdgcn_global_load_lds((gptr_t)(g), (sptr_t)(l), 16, 0, 0)

__device__ __forceinline__ ushort f2b(float f) {
    __hip_bfloat16 h = __float2bfloat16(f);   // RNE
    return *reinterpret_cast<ushort*>(&h);
}
__device__ __forceinline__ float b2f(ushort u) {
    return __uint_as_float(((unsigned)u) << 16);   // exact
}
// packed pair of bf16 (one uint) -> float2: 1 shift + 1 and
__device__ __forceinline__ f32x2 bf2f2(unsigned u) {
    f32x2 r;
    r.x = __uint_as_float(u << 16);
    r.y = __uint_as_float(u & 0xffff0000u);
    return r;
}

// ---------------------------------------------------------------------------
// fused prep + transpose:
//   all 2048 blocks: transpose x (256,32768) fp32 -> Xt (32768,256) bf16
//   blocks < 256 additionally: cast weights to bf16, pack biases
// ---------------------------------------------------------------------------
__global__ __launch_bounds__(256) void prep_transpose(
    const float* __restrict__ x, ushort* __restrict__ Xt,
    const float* __restrict__ wq, const float* __restrict__ wk,
    const float* __restrict__ wv, const float* __restrict__ wo,
    const float* __restrict__ bq, const float* __restrict__ bk,
    const float* __restrict__ bv,
    ushort* __restrict__ Wqkv, ushort* __restrict__ Wo, float* __restrict__ Bqkv)
{
    __shared__ float ts[64][65];
    const int bid = blockIdx.x;             // 0..2047
    const int p0 = (bid >> 2) * 64, c0 = (bid & 3) * 64;
    const int t = threadIdx.x;
    const int pl = t & 63, cl = t >> 6;
    #pragma unroll
    for (int i = 0; i < 16; ++i)
        ts[cl + 4 * i][pl] = x[(size_t)(c0 + cl + 4 * i) * P_TOT + p0 + pl];
    __syncthreads();
    const int pr = t >> 4, cc = (t & 15) * 4;
    #pragma unroll
    for (int i = 0; i < 4; ++i) {
        const int p = pr + 16 * i;
        ushort4 u;
        u.x = f2b(ts[cc + 0][p]); u.y = f2b(ts[cc + 1][p]);
        u.z = f2b(ts[cc + 2][p]); u.w = f2b(ts[cc + 3][p]);
        *(ushort4*)&Xt[(size_t)(p0 + p) * 256 + c0 + cc] = u;
    }
    if (bid < 256) {
        const int i = bid * 256 + t;
        Wqkv[i]          = f2b(wq[i]);
        Wqkv[65536 + i]  = f2b(wk[i]);
        Wqkv[131072 + i] = f2b(wv[i]);
        Wo[i]            = f2b(wo[i]);
        if (i < 256) { Bqkv[i] = bq[i]; Bqkv[256 + i] = bk[i]; Bqkv[512 + i] = bv[i]; }
    }
}

// ---------------------------------------------------------------------------
// GEMM1: QKV[p][o] = sum_c Xt[p][c] * Wqkv[o][c] + Bqkv[o]   (BT form)
// BK=64, XCD swizzle.
// ---------------------------------------------------------------------------
__global__ __launch_bounds__(256) void gemm_qkv(
    ushort* __restrict__ Xt, ushort* __restrict__ Wqkv,
    const float* __restrict__ Bqkv, ushort* __restrict__ QKV)
{
    __shared__ __align__(16) ushort As[128 * 64];   // 16 KB
    __shared__ __align__(16) ushort Bs[128 * 64];   // 16 KB

    const int ord   = blockIdx.x;                    // 0..1535
    const int n_idx = (ord >> 3) % 6;
    const int g     = (ord & 7) + 8 * (ord / 48);    // m-tile 0..255
    const int m0    = g * 128;                       // p
    const int n0    = n_idx * 128;                   // o

    const int t     = threadIdx.x;
    const int lane  = t & 63;
    const int w     = t >> 6;
    const int wm    = (w & 1) * 64;
    const int wn    = (w >> 1) * 64;
    const int l16   = lane & 15;
    const int quad  = lane >> 4;
    const int srow8 = lane >> 3;
    const int scol8 = (lane & 7) * 8;

    f32x4 acc[4][4] = {};

    for (int k0 = 0; k0 < 256; k0 += 64) {
        #pragma unroll
        for (int j = 0; j < 4; ++j) {
            const int i = w * 4 + j;
            GLL16(Xt   + (size_t)(m0 + i * 8 + srow8) * 256 + k0 + scol8, As + i * 512);
            GLL16(Wqkv + (size_t)(n0 + i * 8 + srow8) * 256 + k0 + scol8, Bs + i * 512);
        }
        __syncthreads();
        #pragma unroll
        for (int s = 0; s < 2; ++s) {
            bf16x8 af[4], bfr[4];
            #pragma unroll
            for (int mi = 0; mi < 4; ++mi)
                af[mi] = *(const bf16x8*)(As + (wm + mi * 16 + l16) * 64 + s * 32 + quad * 8);
            #pragma unroll
            for (int ni = 0; ni < 4; ++ni)
                bfr[ni] = *(const bf16x8*)(Bs + (wn + ni * 16 + l16) * 64 + s * 32 + quad * 8);
            #pragma unroll
            for (int mi = 0; mi < 4; ++mi)
                #pragma unroll
                for (int ni = 0; ni < 4; ++ni)
                    acc[mi][ni] = __builtin_amdgcn_mfma_f32_16x16x32_bf16(
                        af[mi], bfr[ni], acc[mi][ni], 0, 0, 0);
        }
        __syncthreads();
    }

    #pragma unroll
    for (int ni = 0; ni < 4; ++ni) {
        const int og = n0 + wn + ni * 16 + l16;
        const float bias = Bqkv[og];
        #pragma unroll
        for (int mi = 0; mi < 4; ++mi)
            #pragma unroll
            for (int r = 0; r < 4; ++r) {
                const int pg = m0 + wm + mi * 16 + quad * 4 + r;
                QKV[(size_t)pg * O_QKV + og] = f2b(acc[mi][ni][r] + bias);
            }
    }
}

// ---------------------------------------------------------------------------
// attention: one wave per pixel, 4 pixels/block. Lane half 0 owns samples
// 0..4, half 1 owns 4..8 (dup sample 4 weighted 0.5 in both halves - exact).
// pk indices computed once by 36 threads into LDS (r7's per-lane recompute
// was ~90 wave-inst of pure redundancy). Dot/PV in packed f32x2 math,
// native __expf + rcp: attn was VALU-issue-bound at 61% busy.
// ---------------------------------------------------------------------------
__global__ __launch_bounds__(256) void attn_k(
    const float* __restrict__ grid, const ushort* __restrict__ QKV,
    ushort* __restrict__ Ab)
{
    __shared__ int pkL[4][12];   // padded: &pkL[w][4] stays 16B-aligned

    const int t    = threadIdx.x;
    const int wid  = t >> 6;       // wave = pixel
    const int lane = t & 63;
    const int half = lane >> 5;    // 0: samples 0..4, 1: samples 4..8
    const int g    = lane & 31;    // 8-channel group
    const int c8   = g * 8;
    const int p    = blockIdx.x * 4 + wid;

    if (t < 36) {
        const int pix = t / 9, k = t - pix * 9;
        const int pp = blockIdx.x * 4 + pix;
        const int h = pp >> 8, w = pp & 255;
        const int kh = k / 3, kw = k - kh * 3;
        const int gr = (h * 3 + kh) * 768 + (w * 3 + kw);
        const float gx = grid[gr * 2 + 0];
        const float gy = grid[gr * 2 + 1];
        int ix = (int)rintf((gx + 1.0f) * 0.5f * 255.0f);
        int iy = (int)rintf((gy + 1.0f) * 0.5f * 127.0f);
        ix = min(max(ix, 0), 255);
        iy = min(max(iy, 0), 127);
        pkL[pix][k] = iy * 256 + ix;
    }
    __syncthreads();

    const int kb = half * 4;
    const int4 pk4 = *(const int4*)&pkL[wid][kb];
    const int  pk5 = pkL[wid][kb + 4];
    const int pks[5] = {pk4.x, pk4.y, pk4.z, pk4.w, pk5};

    // Q fragment converted once to packed f32 pairs
    const uint4 qu = *(const uint4*)&QKV[(size_t)p * O_QKV + c8];
    const f32x2 qf0 = bf2f2(qu.x), qf1 = bf2f2(qu.y),
                qf2 = bf2f2(qu.z), qf3 = bf2f2(qu.w);

    uint4 v8[5];
    float e[5];
    float m = -1e30f;
    #pragma unroll
    for (int j = 0; j < 5; ++j) {
        const size_t base = (size_t)pks[j] * O_QKV + c8;
        const uint4 ku = *(const uint4*)&QKV[base + 256];
        v8[j] = *(const uint4*)&QKV[base + 512];
        f32x2 dd = {0.0f, 0.0f};
        dd = __builtin_elementwise_fma(qf0, bf2f2(ku.x), dd);
        dd = __builtin_elementwise_fma(qf1, bf2f2(ku.y), dd);
        dd = __builtin_elementwise_fma(qf2, bf2f2(ku.z), dd);
        dd = __builtin_elementwise_fma(qf3, bf2f2(ku.w), dd);
        float d = dd.x + dd.y;
        d += __shfl_xor(d, 1);
        d += __shfl_xor(d, 2);      // quad = one head: full 32-ch dot
        e[j] = d * 0.17677669529663687f;   // 32^-0.5
        m = fmaxf(m, e[j]);
    }
    m = fmaxf(m, __shfl_xor(m, 32));   // global max over all 9

    float sum = 0.0f;
    #pragma unroll
    for (int j = 0; j < 5; ++j) {
        float v = __expf(e[j] - m);
        if (j == 0) v = half ? v * 0.5f : v;   // dup sample 4: 0.5 in each half
        if (j == 4) v = half ? v : v * 0.5f;
        e[j] = v;
        sum += v;
    }
    sum += __shfl_xor(sum, 32);
    const float inv = __builtin_amdgcn_rcpf(sum);

    f32x2 o0 = {0,0}, o1 = {0,0}, o2 = {0,0}, o3 = {0,0};
    #pragma unroll
    for (int j = 0; j < 5; ++j) {
        const float a = e[j] * inv;
        const f32x2 a2 = {a, a};
        o0 = __builtin_elementwise_fma(a2, bf2f2(v8[j].x), o0);
        o1 = __builtin_elementwise_fma(a2, bf2f2(v8[j].y), o1);
        o2 = __builtin_elementwise_fma(a2, bf2f2(v8[j].z), o2);
        o3 = __builtin_elementwise_fma(a2, bf2f2(v8[j].w), o3);
    }
    ushort8 r;
    {
        const f32x2 oo[4] = {o0, o1, o2, o3};
        #pragma unroll
        for (int i = 0; i < 4; ++i) {
            const float lo = oo[i].x + __shfl_xor(oo[i].x, 32);
            const float hi = oo[i].y + __shfl_xor(oo[i].y, 32);
            r[2 * i]     = f2b(lo);
            r[2 * i + 1] = f2b(hi);
        }
    }
    if (half == 0)
        *(ushort8*)&Ab[(size_t)p * 256 + c8] = r;
}

// ---------------------------------------------------------------------------
// GEMM2: y[o][p] = sum_c Wo[o][c] * Ab[p][c] + bo[o].  BK=64.
// ---------------------------------------------------------------------------
__global__ __launch_bounds__(256) void gemm_out(
    ushort* __restrict__ Wo, ushort* __restrict__ Ab,
    const float* __restrict__ bo, float* __restrict__ y)
{
    __shared__ __align__(16) ushort As[128 * 64];
    __shared__ __align__(16) ushort Bs[128 * 64];

    const int ord   = blockIdx.x;                  // 0..511
    const int o_idx = (ord >> 3) & 1;
    const int p_idx = (ord & 7) + 8 * (ord >> 4);
    const int m0    = o_idx * 128;                 // o
    const int n0    = p_idx * 128;                 // p

    const int t     = threadIdx.x;
    const int lane  = t & 63;
    const int w     = t >> 6;
    const int wm    = (w & 1) * 64;
    const int wn    = (w >> 1) * 64;
    const int l16   = lane & 15;
    const int quad  = lane >> 4;
    const int srow8 = lane >> 3;
    const int scol8 = (lane & 7) * 8;

    f32x4 acc[4][4] = {};

    for (int k0 = 0; k0 < 256; k0 += 64) {
        #pragma unroll
        for (int j = 0; j < 4; ++j) {
            const int i = w * 4 + j;
            GLL16(Wo + (size_t)(m0 + i * 8 + srow8) * 256 + k0 + scol8, As + i * 512);
            GLL16(Ab + (size_t)(n0 + i * 8 + srow8) * 256 + k0 + scol8, Bs + i * 512);
        }
        __syncthreads();
        #pragma unroll
        for (int s = 0; s < 2; ++s) {
            bf16x8 af[4], bfr[4];
            #pragma unroll
            for (int mi = 0; mi < 4; ++mi)
                af[mi] = *(const bf16x8*)(As + (wm + mi * 16 + l16) * 64 + s * 32 + quad * 8);
            #pragma unroll
            for (int ni = 0; ni < 4; ++ni)
                bfr[ni] = *(const bf16x8*)(Bs + (wn + ni * 16 + l16) * 64 + s * 32 + quad * 8);
            #pragma unroll
            for (int mi = 0; mi < 4; ++mi)
                #pragma unroll
                for (int ni = 0; ni < 4; ++ni)
                    acc[mi][ni] = __builtin_amdgcn_mfma_f32_16x16x32_bf16(
                        af[mi], bfr[ni], acc[mi][ni], 0, 0, 0);
        }
        __syncthreads();
    }

    #pragma unroll
    for (int mi = 0; mi < 4; ++mi)
        #pragma unroll
        for (int r = 0; r < 4; ++r) {
            const int og = m0 + wm + mi * 16 + quad * 4 + r;
            const float bias = bo[og];
            #pragma unroll
            for (int ni = 0; ni < 4; ++ni) {
                const int pg = n0 + wn + ni * 16 + l16;
                y[(size_t)og * P_TOT + pg] = acc[mi][ni][r] + bias;
            }
        }
}

extern "C" void kernel_launch(void* const* d_in, const int* in_sizes, int n_in,
                              void* d_out, int out_size, void* d_ws, size_t ws_size,
                              hipStream_t stream) {
    const float* x    = (const float*)d_in[0];
    const float* grid = (const float*)d_in[1];
    const float* wq   = (const float*)d_in[2];
    const float* bq   = (const float*)d_in[3];
    const float* wk   = (const float*)d_in[4];
    const float* bk   = (const float*)d_in[5];
    const float* wv   = (const float*)d_in[6];
    const float* bv   = (const float*)d_in[7];
    const float* wo   = (const float*)d_in[8];
    const float* bo   = (const float*)d_in[9];
    float* y = (float*)d_out;

    ushort* Xt   = (ushort*)d_ws;                       // 16 MB
    ushort* QKV  = Xt  + (size_t)P_TOT * 256;           // 48 MB
    ushort* Ab   = QKV + (size_t)P_TOT * O_QKV;         // 16 MB
    ushort* Wqkv = Ab  + (size_t)P_TOT * 256;           // 384 KB
    ushort* Wo   = Wqkv + 768 * 256;                    // 128 KB
    float*  Bqkv = (float*)(Wo + 256 * 256);            // 3 KB

    prep_transpose<<<2048, 256, 0, stream>>>(x, Xt, wq, wk, wv, wo, bq, bk, bv,
                                             Wqkv, Wo, Bqkv);
    gemm_qkv<<<1536, 256, 0, stream>>>(Xt, Wqkv, Bqkv, QKV);
    attn_k<<<P_TOT / 4, 256, 0, stream>>>(grid, QKV, Ab);
    gemm_out<<<512, 256, 0, stream>>>(Wo, Ab, bo, y);
}